// Round 9
// baseline (204.344 us; speedup 1.0000x reference)
//
#include <hip/hip_runtime.h>

#define B_   2
#define T_   5
#define N_   4096
#define C_   16
#define D_   128
#define S_   4
#define NS_  16384   // (T-1)*N
#define M_   8192    // B*N
#define EPS_ 1e-5f

// ---- ws layout (fp32 element offsets) ----
#define HX_OFF   0u         // hmax: M*128
#define HN_OFF   1048576u   // hmin: M*128
#define Y_OFF    2097152u   // y: 3*M*128
#define ST_OFF   5242880u   // stats: 2048 floats
#define WL_OFF   5244928u   // [0]=count (int), [1..8192]=straggler query ids
#define ID4_OFF  5253128u   // int4 per query: (i0,i1,i2,cnt) partial hits
#define WP_OFF   5285896u   // packed transposed FC weights: 3*16384 floats
#define PK_OFF   5335048u   // SoA scan data: 2*16384 float4
// st: [0..127] sum_h, [128..255] sumsq_h; branch k: 512+k*512 (+0 sum, +128 sumsq)

#define OUT_FEAT 57344      // element offset of feature within d_out (fp32)

// 144 WGs x 256. WGs [0,128): build pk4[b][j] = (px,py,pz,|p|^2).
// WGs [128,144): pack FC weights transposed; WG 128 zeros st + worklist count.
__global__ __launch_bounds__(256) void k_prep(const float* __restrict__ x,
                                              const float* __restrict__ fw1,
                                              const float* __restrict__ fw2,
                                              const float* __restrict__ fw3,
                                              float* __restrict__ st,
                                              int* __restrict__ wcnt,
                                              float4* __restrict__ wp,
                                              float4* __restrict__ pk4) {
    int tid = threadIdx.x;
    if (blockIdx.x < 128) {
        int row = blockIdx.x * 256 + tid;       // 0..32767
        int b = row >> 14, j = row & 16383;
        const float* p = x + (size_t)b * (T_ * N_ * C_) + N_ * C_ + (size_t)j * 16;
        float4 v = *(const float4*)p;
        float pn = (v.x * v.x + v.y * v.y) + v.z * v.z;   // same expr as scan
        pk4[row] = make_float4(v.x, v.y, v.z, pn);
        return;
    }
    int pb = blockIdx.x - 128;                  // 0..15
    if (pb == 0) {
        #pragma unroll
        for (int i = 0; i < 8; i++) st[tid + 256 * i] = 0.0f;
        if (tid == 0) wcnt[0] = 0;
    }
    int idx = pb * 256 + tid;                   // 0..4095 float4s per FC
    int o = idx >> 5, c4 = idx & 31;
    const float* fws[3] = { fw1, fw2, fw3 };
    #pragma unroll
    for (int k = 0; k < 3; k++)
        wp[k * 4096 + c4 * 128 + o] = *(const float4*)(fws[k] + o * 128 + c4 * 4);
}

// Phase 1: 2048 WGs x 256, one query per wave, CHUNK 0 ONLY (512 pts, L2-hot).
// Complete (cnt==4): gather+conv1, write hmax/hmin over s, stats partials.
// Incomplete: append to worklist with partial hits. Stats: LDS reduce + atomics.
__global__ __launch_bounds__(256) void k_ball1(const float* __restrict__ x,
                                               const float* __restrict__ w,
                                               const float* __restrict__ bias,
                                               const float4* __restrict__ pk4,
                                               float* __restrict__ hx,
                                               float* __restrict__ hn,
                                               float* __restrict__ st,
                                               int* __restrict__ wcnt,
                                               int* __restrict__ wl,
                                               int4* __restrict__ id4) {
    int tid = threadIdx.x;
    int wid = tid >> 6, lane = tid & 63;
    __shared__ float red[2][512];

    float wc0[16], wc1[16];                     // conv1 rows lane, lane+64
    #pragma unroll
    for (int j = 0; j < 4; j++) {
        float4 a = *(const float4*)(w + lane * 16 + j * 4);
        float4 b2 = *(const float4*)(w + (lane + 64) * 16 + j * 4);
        wc0[j*4+0] = a.x;  wc0[j*4+1] = a.y;  wc0[j*4+2] = a.z;  wc0[j*4+3] = a.w;
        wc1[j*4+0] = b2.x; wc1[j*4+1] = b2.y; wc1[j*4+2] = b2.z; wc1[j*4+3] = b2.w;
    }
    float bo0 = bias[lane], bo1 = bias[lane + 64];

    int m = blockIdx.x * 4 + wid;
    int b = m >> 12, q = m & (N_ - 1);
    const float* xb = x + (size_t)b * (T_ * N_ * C_);
    const float* pts = xb + N_ * C_;
    const float4* pk = pk4 + b * 16384;
    float qx = xb[q * 16 + 0];
    float qy = xb[q * 16 + 1];
    float qz = xb[q * 16 + 2];
    float qn = (qx * qx + qy * qy) + qz * qz;

    float4 pv[8];
    #pragma unroll
    for (int u = 0; u < 8; u++) pv[u] = pk[u * 64 + lane];
    unsigned long long mk[8];
    #pragma unroll
    for (int u = 0; u < 8; u++) {
        float dot = (qx * pv[u].x + qy * pv[u].y) + qz * pv[u].z;
        mk[u] = __ballot((qn + pv[u].w) - 2.0f * dot < 1.0f);   // ref form
    }
    int ids[4] = {0, 0, 0, 0};
    int cnt = 0;
    #pragma unroll
    for (int u = 0; u < 8; u++) {
        unsigned long long mask = mk[u];
        while (mask && cnt < 4) {               // wave-uniform
            ids[cnt] = u * 64 + __builtin_ctzll(mask);
            cnt++;
            mask &= (mask - 1);
        }
    }

    float asum0 = 0.0f, asq0 = 0.0f, asum1 = 0.0f, asq1 = 0.0f;
    if (cnt >= 4) {                             // complete: conv + hmax/hmin
        float a0[4], a1[4];
        #pragma unroll
        for (int s = 0; s < 4; s++) {
            const float* rp = pts + (size_t)ids[s] * 16;
            float4 r0 = *(const float4*)(rp);
            float4 r1 = *(const float4*)(rp + 4);
            float4 r2 = *(const float4*)(rp + 8);
            float4 r3 = *(const float4*)(rp + 12);
            float s0 = bo0, s1 = bo1;
            s0 += wc0[0] * r0.x;  s0 += wc0[1] * r0.y;  s0 += wc0[2] * r0.z;  s0 += wc0[3] * r0.w;
            s0 += wc0[4] * r1.x;  s0 += wc0[5] * r1.y;  s0 += wc0[6] * r1.z;  s0 += wc0[7] * r1.w;
            s0 += wc0[8] * r2.x;  s0 += wc0[9] * r2.y;  s0 += wc0[10] * r2.z; s0 += wc0[11] * r2.w;
            s0 += wc0[12] * r3.x; s0 += wc0[13] * r3.y; s0 += wc0[14] * r3.z; s0 += wc0[15] * r3.w;
            s1 += wc1[0] * r0.x;  s1 += wc1[1] * r0.y;  s1 += wc1[2] * r0.z;  s1 += wc1[3] * r0.w;
            s1 += wc1[4] * r1.x;  s1 += wc1[5] * r1.y;  s1 += wc1[6] * r1.z;  s1 += wc1[7] * r1.w;
            s1 += wc1[8] * r2.x;  s1 += wc1[9] * r2.y;  s1 += wc1[10] * r2.z; s1 += wc1[11] * r2.w;
            s1 += wc1[12] * r3.x; s1 += wc1[13] * r3.y; s1 += wc1[14] * r3.z; s1 += wc1[15] * r3.w;
            a0[s] = s0; a1[s] = s1;
        }
        float hx0 = fmaxf(fmaxf(a0[0], a0[1]), fmaxf(a0[2], a0[3]));
        float hn0 = fminf(fminf(a0[0], a0[1]), fminf(a0[2], a0[3]));
        float hx1 = fmaxf(fmaxf(a1[0], a1[1]), fmaxf(a1[2], a1[3]));
        float hn1 = fminf(fminf(a1[0], a1[1]), fminf(a1[2], a1[3]));
        hx[(size_t)m * 128 + lane]      = hx0;
        hx[(size_t)m * 128 + 64 + lane] = hx1;
        hn[(size_t)m * 128 + lane]      = hn0;
        hn[(size_t)m * 128 + 64 + lane] = hn1;
        asum0 = (a0[0] + a0[1]) + (a0[2] + a0[3]);
        asq0  = (a0[0] * a0[0] + a0[1] * a0[1]) + (a0[2] * a0[2] + a0[3] * a0[3]);
        asum1 = (a1[0] + a1[1]) + (a1[2] + a1[3]);
        asq1  = (a1[0] * a1[0] + a1[1] * a1[1]) + (a1[2] * a1[2] + a1[3] * a1[3]);
    } else {                                    // straggler: enqueue
        if (lane == 0) {
            int idx = atomicAdd(wcnt, 1);
            wl[idx] = m;
            id4[m] = make_int4(ids[0], ids[1], ids[2], cnt);
        }
    }

    red[0][wid * 128 + lane]      = asum0;
    red[0][wid * 128 + 64 + lane] = asum1;
    red[1][wid * 128 + lane]      = asq0;
    red[1][wid * 128 + 64 + lane] = asq1;
    __syncthreads();
    if (tid < 128) {
        float s0 = (red[0][tid] + red[0][128 + tid]) + (red[0][256 + tid] + red[0][384 + tid]);
        float s1 = (red[1][tid] + red[1][128 + tid]) + (red[1][256 + tid] + red[1][384 + tid]);
        atomicAdd(&st[tid], s0);
        atomicAdd(&st[128 + tid], s1);
    }
}

// Phase 2: 1024 WGs x 256 grid-striding the worklist. Per entry: 4 waves scan
// 8 chunks each (2-chunk load pipelining), LDS merge of first-4-by-index with
// phase-1 partial, wave 0 does gather+conv+hmax/hmin+stats.
__global__ __launch_bounds__(256) void k_ball2(const float* __restrict__ x,
                                               const float* __restrict__ w,
                                               const float* __restrict__ bias,
                                               const float4* __restrict__ pk4,
                                               float* __restrict__ hx,
                                               float* __restrict__ hn,
                                               float* __restrict__ st,
                                               const int* __restrict__ wcnt,
                                               const int* __restrict__ wl,
                                               const int4* __restrict__ id4) {
    int tid = threadIdx.x;
    int wid = tid >> 6, lane = tid & 63;
    __shared__ int sCnt[4];
    __shared__ int sIds[4][4];

    float wc0[16], wc1[16];
    float bo0 = 0.0f, bo1 = 0.0f;
    if (wid == 0) {                             // only the epilogue wave needs them
        #pragma unroll
        for (int j = 0; j < 4; j++) {
            float4 a = *(const float4*)(w + lane * 16 + j * 4);
            float4 b2 = *(const float4*)(w + (lane + 64) * 16 + j * 4);
            wc0[j*4+0] = a.x;  wc0[j*4+1] = a.y;  wc0[j*4+2] = a.z;  wc0[j*4+3] = a.w;
            wc1[j*4+0] = b2.x; wc1[j*4+1] = b2.y; wc1[j*4+2] = b2.z; wc1[j*4+3] = b2.w;
        }
        bo0 = bias[lane]; bo1 = bias[lane + 64];
    }

    int nstrag = *wcnt;
    for (int e = blockIdx.x; e < nstrag; e += gridDim.x) {
        int m = wl[e];
        int b = m >> 12, q = m & (N_ - 1);
        const float* xb = x + (size_t)b * (T_ * N_ * C_);
        const float* pts = xb + N_ * C_;
        const float4* pk = pk4 + b * 16384;
        float qx = xb[q * 16 + 0];
        float qy = xb[q * 16 + 1];
        float qz = xb[q * 16 + 2];
        float qn = (qx * qx + qy * qy) + qz * qz;

        int cstart = 1 + 8 * wid;
        int cend = cstart + 8; if (cend > 32) cend = 32;
        int myids[4] = {0, 0, 0, 0};
        int myc = 0;
        for (int c = cstart; c < cend && myc < 4; c += 2) {
            bool two = (c + 1 < cend);
            float4 pva[8], pvb[8];
            #pragma unroll
            for (int u = 0; u < 8; u++) pva[u] = pk[c * 512 + u * 64 + lane];
            if (two) {
                #pragma unroll
                for (int u = 0; u < 8; u++) pvb[u] = pk[(c + 1) * 512 + u * 64 + lane];
            }
            unsigned long long ma[8], mb[8];
            #pragma unroll
            for (int u = 0; u < 8; u++) {
                float dot = (qx * pva[u].x + qy * pva[u].y) + qz * pva[u].z;
                ma[u] = __ballot((qn + pva[u].w) - 2.0f * dot < 1.0f);
            }
            if (two) {
                #pragma unroll
                for (int u = 0; u < 8; u++) {
                    float dot = (qx * pvb[u].x + qy * pvb[u].y) + qz * pvb[u].z;
                    mb[u] = __ballot((qn + pvb[u].w) - 2.0f * dot < 1.0f);
                }
            }
            #pragma unroll
            for (int u = 0; u < 8; u++) {
                unsigned long long mask = ma[u];
                while (mask && myc < 4) {
                    myids[myc] = c * 512 + u * 64 + __builtin_ctzll(mask);
                    myc++;
                    mask &= (mask - 1);
                }
            }
            if (two) {
                #pragma unroll
                for (int u = 0; u < 8; u++) {
                    unsigned long long mask = mb[u];
                    while (mask && myc < 4) {
                        myids[myc] = (c + 1) * 512 + u * 64 + __builtin_ctzll(mask);
                        myc++;
                        mask &= (mask - 1);
                    }
                }
            }
        }
        if (lane == 0) {
            sCnt[wid] = myc;
            #pragma unroll
            for (int i = 0; i < 4; i++) sIds[wid][i] = myids[i];
        }
        __syncthreads();

        if (wid == 0) {                         // merge + epilogue on wave 0
            int4 p1 = id4[m];
            int fin[4] = {0, 0, 0, 0};
            int fc = p1.w;                      // 0..3 phase-1 hits (chunk 0)
            if (fc > 0) fin[0] = p1.x;
            if (fc > 1) fin[1] = p1.y;
            if (fc > 2) fin[2] = p1.z;
            #pragma unroll
            for (int w2 = 0; w2 < 4; w2++) {
                int c2 = sCnt[w2];
                for (int i = 0; i < c2 && fc < 4; i++) fin[fc++] = sIds[w2][i];
            }
            if (fc >= 1) {                      // duplicate-first fill
                #pragma unroll
                for (int s = 1; s < 4; s++) if (fc <= s) fin[s] = fin[0];
            }
            float a0[4], a1[4];
            if (fc == 0) {
                #pragma unroll
                for (int s = 0; s < 4; s++) { a0[s] = bo0; a1[s] = bo1; }
            } else {
                #pragma unroll
                for (int s = 0; s < 4; s++) {
                    const float* rp = pts + (size_t)fin[s] * 16;
                    float4 r0 = *(const float4*)(rp);
                    float4 r1 = *(const float4*)(rp + 4);
                    float4 r2 = *(const float4*)(rp + 8);
                    float4 r3 = *(const float4*)(rp + 12);
                    float s0 = bo0, s1 = bo1;
                    s0 += wc0[0] * r0.x;  s0 += wc0[1] * r0.y;  s0 += wc0[2] * r0.z;  s0 += wc0[3] * r0.w;
                    s0 += wc0[4] * r1.x;  s0 += wc0[5] * r1.y;  s0 += wc0[6] * r1.z;  s0 += wc0[7] * r1.w;
                    s0 += wc0[8] * r2.x;  s0 += wc0[9] * r2.y;  s0 += wc0[10] * r2.z; s0 += wc0[11] * r2.w;
                    s0 += wc0[12] * r3.x; s0 += wc0[13] * r3.y; s0 += wc0[14] * r3.z; s0 += wc0[15] * r3.w;
                    s1 += wc1[0] * r0.x;  s1 += wc1[1] * r0.y;  s1 += wc1[2] * r0.z;  s1 += wc1[3] * r0.w;
                    s1 += wc1[4] * r1.x;  s1 += wc1[5] * r1.y;  s1 += wc1[6] * r1.z;  s1 += wc1[7] * r1.w;
                    s1 += wc1[8] * r2.x;  s1 += wc1[9] * r2.y;  s1 += wc1[10] * r2.z; s1 += wc1[11] * r2.w;
                    s1 += wc1[12] * r3.x; s1 += wc1[13] * r3.y; s1 += wc1[14] * r3.z; s1 += wc1[15] * r3.w;
                    a0[s] = s0; a1[s] = s1;
                }
            }
            float hx0 = fmaxf(fmaxf(a0[0], a0[1]), fmaxf(a0[2], a0[3]));
            float hn0 = fminf(fminf(a0[0], a0[1]), fminf(a0[2], a0[3]));
            float hx1 = fmaxf(fmaxf(a1[0], a1[1]), fmaxf(a1[2], a1[3]));
            float hn1 = fminf(fminf(a1[0], a1[1]), fminf(a1[2], a1[3]));
            hx[(size_t)m * 128 + lane]      = hx0;
            hx[(size_t)m * 128 + 64 + lane] = hx1;
            hn[(size_t)m * 128 + lane]      = hn0;
            hn[(size_t)m * 128 + 64 + lane] = hn1;
            float asum0 = (a0[0] + a0[1]) + (a0[2] + a0[3]);
            float asq0  = (a0[0] * a0[0] + a0[1] * a0[1]) + (a0[2] * a0[2] + a0[3] * a0[3]);
            float asum1 = (a1[0] + a1[1]) + (a1[2] + a1[3]);
            float asq1  = (a1[0] * a1[0] + a1[1] * a1[1]) + (a1[2] * a1[2] + a1[3] * a1[3]);
            atomicAdd(&st[lane], asum0);
            atomicAdd(&st[64 + lane], asum1);
            atomicAdd(&st[128 + lane], asq0);
            atomicAdd(&st[192 + lane], asq1);
        }
        __syncthreads();                        // LDS safe for next entry
    }
}

// 512 WG x 256, m-tile 16. Inline bn1 finalize; r = max(sc*hmax, sc*hmin)+sh
// (sign-safe); feature out; 3x 128x128 FC (packed weights + LDS broadcast);
// y write + branch-BN stats.
__global__ __launch_bounds__(256) void k_fc(const float* __restrict__ hx,
                                            const float* __restrict__ hn,
                                            float* __restrict__ st,
                                            const float4* __restrict__ wp,
                                            const float* __restrict__ b1,
                                            const float* __restrict__ b2,
                                            const float* __restrict__ b3,
                                            const float* __restrict__ bng,
                                            const float* __restrict__ bnb,
                                            float* __restrict__ y,
                                            float* __restrict__ out) {
    int tid = threadIdx.x;
    int m0 = blockIdx.x * 16;
    __shared__ float hs[2048];
    __shared__ float scsh[256];

    if (tid < 128) {
        float mean = st[tid] * (1.0f / 32768.0f);
        float var = st[128 + tid] * (1.0f / 32768.0f) - mean * mean;
        float sc = bng[tid] / sqrtf(fmaxf(var, 0.0f) + EPS_);
        scsh[tid] = sc;
        scsh[128 + tid] = bnb[tid] - mean * sc;
    }
    __syncthreads();

    for (int i = tid; i < 16 * 128; i += 256) {
        int ml = i >> 7, o = i & 127;
        float vx = hx[(size_t)(m0 + ml) * 128 + o];
        float vn = hn[(size_t)(m0 + ml) * 128 + o];
        float sc = scsh[o];
        float r = fmaxf(sc * vx, sc * vn) + scsh[128 + o];
        hs[ml * 128 + o] = r;
        out[(size_t)OUT_FEAT + (size_t)(m0 + ml) * 128 + o] = r;
    }
    __syncthreads();

    int o = tid & 127, gr = tid >> 7;
    int mbase = gr * 8;
    float acc[3][8];
    {
        float bb0 = b1[o], bb1 = b2[o], bb2 = b3[o];
        #pragma unroll
        for (int mm = 0; mm < 8; mm++) {
            acc[0][mm] = bb0; acc[1][mm] = bb1; acc[2][mm] = bb2;
        }
    }
    for (int c4 = 0; c4 < 32; c4++) {
        float4 w1v = wp[c4 * 128 + o];
        float4 w2v = wp[4096 + c4 * 128 + o];
        float4 w3v = wp[8192 + c4 * 128 + o];
        const float* hp = &hs[mbase * 128 + c4 * 4];
        #pragma unroll
        for (int mm = 0; mm < 8; mm++) {
            float4 hv = *(const float4*)(hp + mm * 128);
            acc[0][mm] += w1v.x * hv.x; acc[0][mm] += w1v.y * hv.y;
            acc[0][mm] += w1v.z * hv.z; acc[0][mm] += w1v.w * hv.w;
            acc[1][mm] += w2v.x * hv.x; acc[1][mm] += w2v.y * hv.y;
            acc[1][mm] += w2v.z * hv.z; acc[1][mm] += w2v.w * hv.w;
            acc[2][mm] += w3v.x * hv.x; acc[2][mm] += w3v.y * hv.y;
            acc[2][mm] += w3v.z * hv.z; acc[2][mm] += w3v.w * hv.w;
        }
    }
    __syncthreads();
    float psum[3], psq[3];
    #pragma unroll
    for (int k = 0; k < 3; k++) {
        float s = 0.0f, sq = 0.0f;
        float* yk = y + (size_t)k * M_ * 128;
        #pragma unroll
        for (int mm = 0; mm < 8; mm++) {
            float v = acc[k][mm];
            yk[(size_t)(m0 + mbase + mm) * 128 + o] = v;
            s += v; sq += v * v;
        }
        psum[k] = s; psq[k] = sq;
    }
    #pragma unroll
    for (int k = 0; k < 3; k++) {
        hs[(k * 2 + gr) * 128 + o] = psum[k];
        hs[768 + (k * 2 + gr) * 128 + o] = psq[k];
    }
    __syncthreads();
    for (int t = tid; t < 384; t += 256) {
        int k = t >> 7, oo = t & 127;
        float s  = hs[(k * 2) * 128 + oo] + hs[(k * 2 + 1) * 128 + oo];
        float sq = hs[768 + (k * 2) * 128 + oo] + hs[768 + (k * 2 + 1) * 128 + oo];
        int base = 512 + k * 512;
        atomicAdd(&st[base + oo], s);
        atomicAdd(&st[base + 128 + oo], sq);
    }
}

// 512 WG x 256 (4 waves, 4 rows/wave). Inline branch-BN finalize, bn+relu,
// head matmuls, 7 fp32 outputs per row.
__global__ __launch_bounds__(256) void k_heads(const float* __restrict__ y,
                                               const float* __restrict__ st,
                                               const float* __restrict__ wce, const float* __restrict__ bce,
                                               const float* __restrict__ wlwh, const float* __restrict__ blwh,
                                               const float* __restrict__ wth, const float* __restrict__ bth,
                                               const float* __restrict__ bng, const float* __restrict__ bnb,
                                               float* __restrict__ out) {
    int tid = threadIdx.x;
    __shared__ float bsc[768];
    for (int t = tid; t < 384; t += 256) {
        int k = t >> 7, o = t & 127;
        int base = 512 + k * 512;
        float mean = st[base + o] * (1.0f / 8192.0f);
        float var = st[base + 128 + o] * (1.0f / 8192.0f) - mean * mean;
        float sc = bng[o] / sqrtf(fmaxf(var, 0.0f) + EPS_);
        bsc[k * 256 + o] = sc;
        bsc[k * 256 + 128 + o] = bnb[o] - mean * sc;
    }
    __syncthreads();

    int wave = tid >> 6, lane = tid & 63;
    const float* y1 = y;
    const float* y2 = y + (size_t)M_ * D_;
    const float* y3 = y + 2 * (size_t)M_ * D_;
    #pragma unroll
    for (int i = 0; i < 4; i++) {
        int m = blockIdx.x * 16 + wave * 4 + i;
        float p[7] = {0, 0, 0, 0, 0, 0, 0};
        #pragma unroll
        for (int cc = 0; cc < 2; cc++) {
            int c = lane + 64 * cc;
            float v1 = fmaxf(y1[(size_t)m * D_ + c] * bsc[c] + bsc[128 + c], 0.0f);
            float v2 = fmaxf(y2[(size_t)m * D_ + c] * bsc[256 + c] + bsc[384 + c], 0.0f);
            float v3 = fmaxf(y3[(size_t)m * D_ + c] * bsc[512 + c] + bsc[640 + c], 0.0f);
            p[0] += v1 * wce[c];
            p[1] += v1 * wce[128 + c];
            p[2] += v1 * wce[256 + c];
            p[3] += v2 * wlwh[c];
            p[4] += v2 * wlwh[128 + c];
            p[5] += v2 * wlwh[256 + c];
            p[6] += v3 * wth[c];
        }
        #pragma unroll
        for (int off = 32; off > 0; off >>= 1) {
            #pragma unroll
            for (int j = 0; j < 7; j++) p[j] += __shfl_xor(p[j], off);
        }
        if (lane == 0) {
            out[m * 7 + 0] = p[0] + bce[0];
            out[m * 7 + 1] = p[1] + bce[1];
            out[m * 7 + 2] = p[2] + bce[2];
            out[m * 7 + 3] = p[3] + blwh[0];
            out[m * 7 + 4] = p[4] + blwh[1];
            out[m * 7 + 5] = p[5] + blwh[2];
            out[m * 7 + 6] = p[6] + bth[0];
        }
    }
}

extern "C" void kernel_launch(void* const* d_in, const int* in_sizes, int n_in,
                              void* d_out, int out_size, void* d_ws, size_t ws_size,
                              hipStream_t stream) {
    (void)in_sizes; (void)n_in; (void)out_size; (void)ws_size;
    const float* x        = (const float*)d_in[0];
    const float* conv1_w  = (const float*)d_in[1];
    const float* conv1_b  = (const float*)d_in[2];
    const float* bn_g     = (const float*)d_in[3];
    const float* bn_b     = (const float*)d_in[4];
    const float* fc1_w    = (const float*)d_in[5];
    const float* fc1_b    = (const float*)d_in[6];
    const float* fc_ce_w  = (const float*)d_in[7];
    const float* fc_ce_b  = (const float*)d_in[8];
    const float* fc2_w    = (const float*)d_in[9];
    const float* fc2_b    = (const float*)d_in[10];
    const float* fc_lwh_w = (const float*)d_in[11];
    const float* fc_lwh_b = (const float*)d_in[12];
    const float* fc3_w    = (const float*)d_in[13];
    const float* fc3_b    = (const float*)d_in[14];
    const float* fc_th_w  = (const float*)d_in[15];
    const float* fc_th_b  = (const float*)d_in[16];

    float* ws = (float*)d_ws;
    float* hx = ws + HX_OFF;
    float* hn = ws + HN_OFF;
    float* y  = ws + Y_OFF;
    float* st = ws + ST_OFF;
    int*  wcnt = (int*)(ws + WL_OFF);
    int*  wl   = wcnt + 1;
    int4* id4  = (int4*)(ws + ID4_OFF);
    float4* wp  = (float4*)(ws + WP_OFF);
    float4* pk4 = (float4*)(ws + PK_OFF);
    float* out = (float*)d_out;

    hipLaunchKernelGGL(k_prep,  dim3(144),  dim3(256), 0, stream,
                       x, fc1_w, fc2_w, fc3_w, st, wcnt, wp, pk4);
    hipLaunchKernelGGL(k_ball1, dim3(2048), dim3(256), 0, stream,
                       x, conv1_w, conv1_b, pk4, hx, hn, st, wcnt, wl, id4);
    hipLaunchKernelGGL(k_ball2, dim3(1024), dim3(256), 0, stream,
                       x, conv1_w, conv1_b, pk4, hx, hn, st, wcnt, wl, id4);
    hipLaunchKernelGGL(k_fc,    dim3(512),  dim3(256), 0, stream, hx, hn, st, wp,
                       fc1_b, fc2_b, fc3_b, bn_g, bn_b, y, out);
    hipLaunchKernelGGL(k_heads, dim3(512),  dim3(256), 0, stream, y, st,
                       fc_ce_w, fc_ce_b, fc_lwh_w, fc_lwh_b, fc_th_w, fc_th_b, bn_g, bn_b, out);
}

// Round 10
// 147.339 us; speedup vs baseline: 1.3869x; 1.3869x over previous
//
#include <hip/hip_runtime.h>

#define B_   2
#define T_   5
#define N_   4096
#define C_   16
#define D_   128
#define S_   4
#define NS_  16384   // (T-1)*N
#define M_   8192    // B*N
#define EPS_ 1e-5f
#define NPART 32     // atomic partial buffers (contention killer)

// ---- ws layout (fp32 element offsets) ----
#define HX_OFF   0u         // hmax: M*128
#define HN_OFF   1048576u   // hmin: M*128
#define Y_OFF    2097152u   // y: 3*M*128
#define ST_OFF   5242880u   // stats partials: 32*256 (bn1) + 32*768 (branch) = 32768
#define WL_OFF   5275648u   // [0]=count (int), [1..8192]=straggler ids
#define ID4_OFF  5283848u   // int4 per query: (i0,i1,i2,cnt)
#define WP_OFF   5316616u   // packed transposed FC weights: 3*16384
#define PK_OFF   5365768u   // SoA scan data: 2*16384 float4
// bn1 partial p: st[p*256 + (0..127 sum | 128..255 sumsq)]
// branch partial p, branch k: st[8192 + p*768 + k*256 + (0..127 sum | 128..255 sq)]

#define OUT_FEAT 57344      // element offset of feature within d_out (fp32)

// 144 WGs x 256. WGs [0,128): pk4[b][j] = (px,py,pz,|p|^2).
// WGs [128,144): zero all 32768 stats floats + wcnt; pack FC weights transposed.
__global__ __launch_bounds__(256) void k_prep(const float* __restrict__ x,
                                              const float* __restrict__ fw1,
                                              const float* __restrict__ fw2,
                                              const float* __restrict__ fw3,
                                              float* __restrict__ st,
                                              int* __restrict__ wcnt,
                                              float4* __restrict__ wp,
                                              float4* __restrict__ pk4) {
    int tid = threadIdx.x;
    if (blockIdx.x < 128) {
        int row = blockIdx.x * 256 + tid;       // 0..32767
        int b = row >> 14, j = row & 16383;
        const float* p = x + (size_t)b * (T_ * N_ * C_) + N_ * C_ + (size_t)j * 16;
        float4 v = *(const float4*)p;
        float pn = (v.x * v.x + v.y * v.y) + v.z * v.z;   // same expr as scan
        pk4[row] = make_float4(v.x, v.y, v.z, pn);
        return;
    }
    int pb = blockIdx.x - 128;                  // 0..15
    int t0 = pb * 256 + tid;                    // 0..4095
    #pragma unroll
    for (int i = 0; i < 8; i++) st[t0 + 4096 * i] = 0.0f;   // 32768 floats
    if (pb == 0 && tid == 0) wcnt[0] = 0;
    int o = t0 >> 5, c4 = t0 & 31;              // 0..4095 float4s per FC
    const float* fws[3] = { fw1, fw2, fw3 };
    #pragma unroll
    for (int k = 0; k < 3; k++)
        wp[k * 4096 + c4 * 128 + o] = *(const float4*)(fws[k] + o * 128 + c4 * 4);
}

// Phase 1: 512 WGs x 256, 4 queries per wave, CHUNK 0 ONLY (512 pts, L2-hot).
// Complete (cnt==4): gather+conv1 -> hmax/hmin, stats in registers.
// Incomplete: enqueue. One LDS reduce + ONE atomic set per block into a
// partial buffer (blockIdx%32) — per-address RMW = 16, not 2048.
__global__ __launch_bounds__(256) void k_ball1(const float* __restrict__ x,
                                               const float* __restrict__ w,
                                               const float* __restrict__ bias,
                                               const float4* __restrict__ pk4,
                                               float* __restrict__ hx,
                                               float* __restrict__ hn,
                                               float* __restrict__ st,
                                               int* __restrict__ wcnt,
                                               int* __restrict__ wl,
                                               int4* __restrict__ id4) {
    int tid = threadIdx.x;
    int wid = tid >> 6, lane = tid & 63;
    __shared__ float red[2][512];

    float wc0[16], wc1[16];                     // conv1 rows lane, lane+64
    #pragma unroll
    for (int j = 0; j < 4; j++) {
        float4 a = *(const float4*)(w + lane * 16 + j * 4);
        float4 b2 = *(const float4*)(w + (lane + 64) * 16 + j * 4);
        wc0[j*4+0] = a.x;  wc0[j*4+1] = a.y;  wc0[j*4+2] = a.z;  wc0[j*4+3] = a.w;
        wc1[j*4+0] = b2.x; wc1[j*4+1] = b2.y; wc1[j*4+2] = b2.z; wc1[j*4+3] = b2.w;
    }
    float bo0 = bias[lane], bo1 = bias[lane + 64];

    float asum0 = 0.0f, asq0 = 0.0f, asum1 = 0.0f, asq1 = 0.0f;
    for (int qi = 0; qi < 4; qi++) {
        int m = (blockIdx.x * 4 + wid) * 4 + qi;   // covers 0..8191
        int b = m >> 12, q = m & (N_ - 1);
        const float* xb = x + (size_t)b * (T_ * N_ * C_);
        const float* pts = xb + N_ * C_;
        const float4* pk = pk4 + b * 16384;
        float qx = xb[q * 16 + 0];
        float qy = xb[q * 16 + 1];
        float qz = xb[q * 16 + 2];
        float qn = (qx * qx + qy * qy) + qz * qz;

        float4 pv[8];
        #pragma unroll
        for (int u = 0; u < 8; u++) pv[u] = pk[u * 64 + lane];
        unsigned long long mk[8];
        #pragma unroll
        for (int u = 0; u < 8; u++) {
            float dot = (qx * pv[u].x + qy * pv[u].y) + qz * pv[u].z;
            mk[u] = __ballot((qn + pv[u].w) - 2.0f * dot < 1.0f);   // ref form
        }
        int ids[4] = {0, 0, 0, 0};
        int cnt = 0;
        #pragma unroll
        for (int u = 0; u < 8; u++) {
            unsigned long long mask = mk[u];
            while (mask && cnt < 4) {           // wave-uniform
                ids[cnt] = u * 64 + __builtin_ctzll(mask);
                cnt++;
                mask &= (mask - 1);
            }
        }

        if (cnt >= 4) {                         // complete: conv + hmax/hmin
            float a0[4], a1[4];
            #pragma unroll
            for (int s = 0; s < 4; s++) {
                const float* rp = pts + (size_t)ids[s] * 16;
                float4 r0 = *(const float4*)(rp);
                float4 r1 = *(const float4*)(rp + 4);
                float4 r2 = *(const float4*)(rp + 8);
                float4 r3 = *(const float4*)(rp + 12);
                float s0 = bo0, s1 = bo1;
                s0 += wc0[0] * r0.x;  s0 += wc0[1] * r0.y;  s0 += wc0[2] * r0.z;  s0 += wc0[3] * r0.w;
                s0 += wc0[4] * r1.x;  s0 += wc0[5] * r1.y;  s0 += wc0[6] * r1.z;  s0 += wc0[7] * r1.w;
                s0 += wc0[8] * r2.x;  s0 += wc0[9] * r2.y;  s0 += wc0[10] * r2.z; s0 += wc0[11] * r2.w;
                s0 += wc0[12] * r3.x; s0 += wc0[13] * r3.y; s0 += wc0[14] * r3.z; s0 += wc0[15] * r3.w;
                s1 += wc1[0] * r0.x;  s1 += wc1[1] * r0.y;  s1 += wc1[2] * r0.z;  s1 += wc1[3] * r0.w;
                s1 += wc1[4] * r1.x;  s1 += wc1[5] * r1.y;  s1 += wc1[6] * r1.z;  s1 += wc1[7] * r1.w;
                s1 += wc1[8] * r2.x;  s1 += wc1[9] * r2.y;  s1 += wc1[10] * r2.z; s1 += wc1[11] * r2.w;
                s1 += wc1[12] * r3.x; s1 += wc1[13] * r3.y; s1 += wc1[14] * r3.z; s1 += wc1[15] * r3.w;
                a0[s] = s0; a1[s] = s1;
            }
            hx[(size_t)m * 128 + lane]      = fmaxf(fmaxf(a0[0], a0[1]), fmaxf(a0[2], a0[3]));
            hx[(size_t)m * 128 + 64 + lane] = fmaxf(fmaxf(a1[0], a1[1]), fmaxf(a1[2], a1[3]));
            hn[(size_t)m * 128 + lane]      = fminf(fminf(a0[0], a0[1]), fminf(a0[2], a0[3]));
            hn[(size_t)m * 128 + 64 + lane] = fminf(fminf(a1[0], a1[1]), fminf(a1[2], a1[3]));
            asum0 += (a0[0] + a0[1]) + (a0[2] + a0[3]);
            asq0  += (a0[0] * a0[0] + a0[1] * a0[1]) + (a0[2] * a0[2] + a0[3] * a0[3]);
            asum1 += (a1[0] + a1[1]) + (a1[2] + a1[3]);
            asq1  += (a1[0] * a1[0] + a1[1] * a1[1]) + (a1[2] * a1[2] + a1[3] * a1[3]);
        } else {                                // straggler: enqueue
            if (lane == 0) {
                int idx = atomicAdd(wcnt, 1);
                wl[idx] = m;
                id4[m] = make_int4(ids[0], ids[1], ids[2], cnt);
            }
        }
    }

    red[0][wid * 128 + lane]      = asum0;
    red[0][wid * 128 + 64 + lane] = asum1;
    red[1][wid * 128 + lane]      = asq0;
    red[1][wid * 128 + 64 + lane] = asq1;
    __syncthreads();
    if (tid < 128) {
        float* stp = st + (blockIdx.x & (NPART - 1)) * 256;
        float s0 = (red[0][tid] + red[0][128 + tid]) + (red[0][256 + tid] + red[0][384 + tid]);
        float s1 = (red[1][tid] + red[1][128 + tid]) + (red[1][256 + tid] + red[1][384 + tid]);
        atomicAdd(&stp[tid], s0);
        atomicAdd(&stp[128 + tid], s1);
    }
}

// Phase 2: 1024 WGs x 256 grid-striding the worklist. 4 waves scan 8 chunks
// each (2-deep pipelining), LDS merge first-4-by-index with phase-1 partial,
// wave 0: gather+conv+hmax/hmin. Stats register-accumulated across entries;
// ONE atomic set per block at the end (partial buffer blockIdx%32).
__global__ __launch_bounds__(256) void k_ball2(const float* __restrict__ x,
                                               const float* __restrict__ w,
                                               const float* __restrict__ bias,
                                               const float4* __restrict__ pk4,
                                               float* __restrict__ hx,
                                               float* __restrict__ hn,
                                               float* __restrict__ st,
                                               const int* __restrict__ wcnt,
                                               const int* __restrict__ wl,
                                               const int4* __restrict__ id4) {
    int tid = threadIdx.x;
    int wid = tid >> 6, lane = tid & 63;
    __shared__ int sCnt[4];
    __shared__ int sIds[4][4];

    float wc0[16], wc1[16];
    float bo0 = 0.0f, bo1 = 0.0f;
    if (wid == 0) {
        #pragma unroll
        for (int j = 0; j < 4; j++) {
            float4 a = *(const float4*)(w + lane * 16 + j * 4);
            float4 b2 = *(const float4*)(w + (lane + 64) * 16 + j * 4);
            wc0[j*4+0] = a.x;  wc0[j*4+1] = a.y;  wc0[j*4+2] = a.z;  wc0[j*4+3] = a.w;
            wc1[j*4+0] = b2.x; wc1[j*4+1] = b2.y; wc1[j*4+2] = b2.z; wc1[j*4+3] = b2.w;
        }
        bo0 = bias[lane]; bo1 = bias[lane + 64];
    }
    float asum0 = 0.0f, asq0 = 0.0f, asum1 = 0.0f, asq1 = 0.0f;

    int nstrag = *wcnt;
    for (int e = blockIdx.x; e < nstrag; e += gridDim.x) {
        int m = wl[e];
        int b = m >> 12, q = m & (N_ - 1);
        const float* xb = x + (size_t)b * (T_ * N_ * C_);
        const float* pts = xb + N_ * C_;
        const float4* pk = pk4 + b * 16384;
        float qx = xb[q * 16 + 0];
        float qy = xb[q * 16 + 1];
        float qz = xb[q * 16 + 2];
        float qn = (qx * qx + qy * qy) + qz * qz;

        int cstart = 1 + 8 * wid;
        int cend = cstart + 8; if (cend > 32) cend = 32;
        int myids[4] = {0, 0, 0, 0};
        int myc = 0;
        for (int c = cstart; c < cend && myc < 4; c += 2) {
            bool two = (c + 1 < cend);
            float4 pva[8], pvb[8];
            #pragma unroll
            for (int u = 0; u < 8; u++) pva[u] = pk[c * 512 + u * 64 + lane];
            if (two) {
                #pragma unroll
                for (int u = 0; u < 8; u++) pvb[u] = pk[(c + 1) * 512 + u * 64 + lane];
            }
            unsigned long long ma[8], mb[8];
            #pragma unroll
            for (int u = 0; u < 8; u++) {
                float dot = (qx * pva[u].x + qy * pva[u].y) + qz * pva[u].z;
                ma[u] = __ballot((qn + pva[u].w) - 2.0f * dot < 1.0f);
            }
            if (two) {
                #pragma unroll
                for (int u = 0; u < 8; u++) {
                    float dot = (qx * pvb[u].x + qy * pvb[u].y) + qz * pvb[u].z;
                    mb[u] = __ballot((qn + pvb[u].w) - 2.0f * dot < 1.0f);
                }
            }
            #pragma unroll
            for (int u = 0; u < 8; u++) {
                unsigned long long mask = ma[u];
                while (mask && myc < 4) {
                    myids[myc] = c * 512 + u * 64 + __builtin_ctzll(mask);
                    myc++;
                    mask &= (mask - 1);
                }
            }
            if (two) {
                #pragma unroll
                for (int u = 0; u < 8; u++) {
                    unsigned long long mask = mb[u];
                    while (mask && myc < 4) {
                        myids[myc] = (c + 1) * 512 + u * 64 + __builtin_ctzll(mask);
                        myc++;
                        mask &= (mask - 1);
                    }
                }
            }
        }
        if (lane == 0) {
            sCnt[wid] = myc;
            #pragma unroll
            for (int i = 0; i < 4; i++) sIds[wid][i] = myids[i];
        }
        __syncthreads();

        if (wid == 0) {                         // merge + epilogue on wave 0
            int4 p1 = id4[m];
            int fin[4] = {0, 0, 0, 0};
            int fc = p1.w;
            if (fc > 0) fin[0] = p1.x;
            if (fc > 1) fin[1] = p1.y;
            if (fc > 2) fin[2] = p1.z;
            #pragma unroll
            for (int w2 = 0; w2 < 4; w2++) {
                int c2 = sCnt[w2];
                for (int i = 0; i < c2 && fc < 4; i++) fin[fc++] = sIds[w2][i];
            }
            if (fc >= 1) {
                #pragma unroll
                for (int s = 1; s < 4; s++) if (fc <= s) fin[s] = fin[0];
            }
            float a0[4], a1[4];
            if (fc == 0) {
                #pragma unroll
                for (int s = 0; s < 4; s++) { a0[s] = bo0; a1[s] = bo1; }
            } else {
                #pragma unroll
                for (int s = 0; s < 4; s++) {
                    const float* rp = pts + (size_t)fin[s] * 16;
                    float4 r0 = *(const float4*)(rp);
                    float4 r1 = *(const float4*)(rp + 4);
                    float4 r2 = *(const float4*)(rp + 8);
                    float4 r3 = *(const float4*)(rp + 12);
                    float s0 = bo0, s1 = bo1;
                    s0 += wc0[0] * r0.x;  s0 += wc0[1] * r0.y;  s0 += wc0[2] * r0.z;  s0 += wc0[3] * r0.w;
                    s0 += wc0[4] * r1.x;  s0 += wc0[5] * r1.y;  s0 += wc0[6] * r1.z;  s0 += wc0[7] * r1.w;
                    s0 += wc0[8] * r2.x;  s0 += wc0[9] * r2.y;  s0 += wc0[10] * r2.z; s0 += wc0[11] * r2.w;
                    s0 += wc0[12] * r3.x; s0 += wc0[13] * r3.y; s0 += wc0[14] * r3.z; s0 += wc0[15] * r3.w;
                    s1 += wc1[0] * r0.x;  s1 += wc1[1] * r0.y;  s1 += wc1[2] * r0.z;  s1 += wc1[3] * r0.w;
                    s1 += wc1[4] * r1.x;  s1 += wc1[5] * r1.y;  s1 += wc1[6] * r1.z;  s1 += wc1[7] * r1.w;
                    s1 += wc1[8] * r2.x;  s1 += wc1[9] * r2.y;  s1 += wc1[10] * r2.z; s1 += wc1[11] * r2.w;
                    s1 += wc1[12] * r3.x; s1 += wc1[13] * r3.y; s1 += wc1[14] * r3.z; s1 += wc1[15] * r3.w;
                    a0[s] = s0; a1[s] = s1;
                }
            }
            hx[(size_t)m * 128 + lane]      = fmaxf(fmaxf(a0[0], a0[1]), fmaxf(a0[2], a0[3]));
            hx[(size_t)m * 128 + 64 + lane] = fmaxf(fmaxf(a1[0], a1[1]), fmaxf(a1[2], a1[3]));
            hn[(size_t)m * 128 + lane]      = fminf(fminf(a0[0], a0[1]), fminf(a0[2], a0[3]));
            hn[(size_t)m * 128 + 64 + lane] = fminf(fminf(a1[0], a1[1]), fminf(a1[2], a1[3]));
            asum0 += (a0[0] + a0[1]) + (a0[2] + a0[3]);
            asq0  += (a0[0] * a0[0] + a0[1] * a0[1]) + (a0[2] * a0[2] + a0[3] * a0[3]);
            asum1 += (a1[0] + a1[1]) + (a1[2] + a1[3]);
            asq1  += (a1[0] * a1[0] + a1[1] * a1[1]) + (a1[2] * a1[2] + a1[3] * a1[3]);
        }
        __syncthreads();                        // LDS safe for next entry
    }
    if (wid == 0) {                             // one atomic set per block
        float* stp = st + (blockIdx.x & (NPART - 1)) * 256;
        atomicAdd(&stp[lane], asum0);
        atomicAdd(&stp[64 + lane], asum1);
        atomicAdd(&stp[128 + lane], asq0);
        atomicAdd(&stp[192 + lane], asq1);
    }
}

// 512 WG x 256, m-tile 16. bn1 finalize from 32 partials; r = max(sc*hmax,
// sc*hmin)+sh; feature out; 3x 128x128 FC (packed weights + LDS broadcast);
// y write + branch stats into partial buffer blockIdx%32.
__global__ __launch_bounds__(256) void k_fc(const float* __restrict__ hx,
                                            const float* __restrict__ hn,
                                            float* __restrict__ st,
                                            const float4* __restrict__ wp,
                                            const float* __restrict__ b1,
                                            const float* __restrict__ b2,
                                            const float* __restrict__ b3,
                                            const float* __restrict__ bng,
                                            const float* __restrict__ bnb,
                                            float* __restrict__ y,
                                            float* __restrict__ out) {
    int tid = threadIdx.x;
    int m0 = blockIdx.x * 16;
    __shared__ float hs[2048];
    __shared__ float scsh[256];

    if (tid < 128) {                            // bn1 finalize from partials
        float s = 0.0f, q2 = 0.0f;
        #pragma unroll
        for (int p = 0; p < NPART; p++) {
            s  += st[p * 256 + tid];
            q2 += st[p * 256 + 128 + tid];
        }
        float mean = s * (1.0f / 32768.0f);
        float var = q2 * (1.0f / 32768.0f) - mean * mean;
        float sc = bng[tid] / sqrtf(fmaxf(var, 0.0f) + EPS_);
        scsh[tid] = sc;
        scsh[128 + tid] = bnb[tid] - mean * sc;
    }
    __syncthreads();

    for (int i = tid; i < 16 * 128; i += 256) {
        int ml = i >> 7, o = i & 127;
        float vx = hx[(size_t)(m0 + ml) * 128 + o];
        float vn = hn[(size_t)(m0 + ml) * 128 + o];
        float sc = scsh[o];
        float r = fmaxf(sc * vx, sc * vn) + scsh[128 + o];
        hs[ml * 128 + o] = r;
        out[(size_t)OUT_FEAT + (size_t)(m0 + ml) * 128 + o] = r;
    }
    __syncthreads();

    int o = tid & 127, gr = tid >> 7;
    int mbase = gr * 8;
    float acc[3][8];
    {
        float bb0 = b1[o], bb1 = b2[o], bb2 = b3[o];
        #pragma unroll
        for (int mm = 0; mm < 8; mm++) {
            acc[0][mm] = bb0; acc[1][mm] = bb1; acc[2][mm] = bb2;
        }
    }
    for (int c4 = 0; c4 < 32; c4++) {
        float4 w1v = wp[c4 * 128 + o];
        float4 w2v = wp[4096 + c4 * 128 + o];
        float4 w3v = wp[8192 + c4 * 128 + o];
        const float* hp = &hs[mbase * 128 + c4 * 4];
        #pragma unroll
        for (int mm = 0; mm < 8; mm++) {
            float4 hv = *(const float4*)(hp + mm * 128);
            acc[0][mm] += w1v.x * hv.x; acc[0][mm] += w1v.y * hv.y;
            acc[0][mm] += w1v.z * hv.z; acc[0][mm] += w1v.w * hv.w;
            acc[1][mm] += w2v.x * hv.x; acc[1][mm] += w2v.y * hv.y;
            acc[1][mm] += w2v.z * hv.z; acc[1][mm] += w2v.w * hv.w;
            acc[2][mm] += w3v.x * hv.x; acc[2][mm] += w3v.y * hv.y;
            acc[2][mm] += w3v.z * hv.z; acc[2][mm] += w3v.w * hv.w;
        }
    }
    __syncthreads();
    float psum[3], psq[3];
    #pragma unroll
    for (int k = 0; k < 3; k++) {
        float s = 0.0f, sq = 0.0f;
        float* yk = y + (size_t)k * M_ * 128;
        #pragma unroll
        for (int mm = 0; mm < 8; mm++) {
            float v = acc[k][mm];
            yk[(size_t)(m0 + mbase + mm) * 128 + o] = v;
            s += v; sq += v * v;
        }
        psum[k] = s; psq[k] = sq;
    }
    #pragma unroll
    for (int k = 0; k < 3; k++) {
        hs[(k * 2 + gr) * 128 + o] = psum[k];
        hs[768 + (k * 2 + gr) * 128 + o] = psq[k];
    }
    __syncthreads();
    float* bp = st + 8192 + (blockIdx.x & (NPART - 1)) * 768;
    for (int t = tid; t < 384; t += 256) {
        int k = t >> 7, oo = t & 127;
        float s  = hs[(k * 2) * 128 + oo] + hs[(k * 2 + 1) * 128 + oo];
        float sq = hs[768 + (k * 2) * 128 + oo] + hs[768 + (k * 2 + 1) * 128 + oo];
        atomicAdd(&bp[k * 256 + oo], s);
        atomicAdd(&bp[k * 256 + 128 + oo], sq);
    }
}

// 512 WG x 256 (4 waves, 4 rows/wave). Branch-BN finalize from 32 partials,
// bn+relu, head matmuls, 7 fp32 outputs per row.
__global__ __launch_bounds__(256) void k_heads(const float* __restrict__ y,
                                               const float* __restrict__ st,
                                               const float* __restrict__ wce, const float* __restrict__ bce,
                                               const float* __restrict__ wlwh, const float* __restrict__ blwh,
                                               const float* __restrict__ wth, const float* __restrict__ bth,
                                               const float* __restrict__ bng, const float* __restrict__ bnb,
                                               float* __restrict__ out) {
    int tid = threadIdx.x;
    __shared__ float bsc[768];
    for (int t = tid; t < 384; t += 256) {
        int k = t >> 7, o = t & 127;
        float s = 0.0f, q2 = 0.0f;
        #pragma unroll
        for (int p = 0; p < NPART; p++) {
            const float* bp = st + 8192 + p * 768 + k * 256;
            s  += bp[o];
            q2 += bp[128 + o];
        }
        float mean = s * (1.0f / 8192.0f);
        float var = q2 * (1.0f / 8192.0f) - mean * mean;
        float sc = bng[o] / sqrtf(fmaxf(var, 0.0f) + EPS_);
        bsc[k * 256 + o] = sc;
        bsc[k * 256 + 128 + o] = bnb[o] - mean * sc;
    }
    __syncthreads();

    int wave = tid >> 6, lane = tid & 63;
    const float* y1 = y;
    const float* y2 = y + (size_t)M_ * D_;
    const float* y3 = y + 2 * (size_t)M_ * D_;
    #pragma unroll
    for (int i = 0; i < 4; i++) {
        int m = blockIdx.x * 16 + wave * 4 + i;
        float p[7] = {0, 0, 0, 0, 0, 0, 0};
        #pragma unroll
        for (int cc = 0; cc < 2; cc++) {
            int c = lane + 64 * cc;
            float v1 = fmaxf(y1[(size_t)m * D_ + c] * bsc[c] + bsc[128 + c], 0.0f);
            float v2 = fmaxf(y2[(size_t)m * D_ + c] * bsc[256 + c] + bsc[384 + c], 0.0f);
            float v3 = fmaxf(y3[(size_t)m * D_ + c] * bsc[512 + c] + bsc[640 + c], 0.0f);
            p[0] += v1 * wce[c];
            p[1] += v1 * wce[128 + c];
            p[2] += v1 * wce[256 + c];
            p[3] += v2 * wlwh[c];
            p[4] += v2 * wlwh[128 + c];
            p[5] += v2 * wlwh[256 + c];
            p[6] += v3 * wth[c];
        }
        #pragma unroll
        for (int off = 32; off > 0; off >>= 1) {
            #pragma unroll
            for (int j = 0; j < 7; j++) p[j] += __shfl_xor(p[j], off);
        }
        if (lane == 0) {
            out[m * 7 + 0] = p[0] + bce[0];
            out[m * 7 + 1] = p[1] + bce[1];
            out[m * 7 + 2] = p[2] + bce[2];
            out[m * 7 + 3] = p[3] + blwh[0];
            out[m * 7 + 4] = p[4] + blwh[1];
            out[m * 7 + 5] = p[5] + blwh[2];
            out[m * 7 + 6] = p[6] + bth[0];
        }
    }
}

extern "C" void kernel_launch(void* const* d_in, const int* in_sizes, int n_in,
                              void* d_out, int out_size, void* d_ws, size_t ws_size,
                              hipStream_t stream) {
    (void)in_sizes; (void)n_in; (void)out_size; (void)ws_size;
    const float* x        = (const float*)d_in[0];
    const float* conv1_w  = (const float*)d_in[1];
    const float* conv1_b  = (const float*)d_in[2];
    const float* bn_g     = (const float*)d_in[3];
    const float* bn_b     = (const float*)d_in[4];
    const float* fc1_w    = (const float*)d_in[5];
    const float* fc1_b    = (const float*)d_in[6];
    const float* fc_ce_w  = (const float*)d_in[7];
    const float* fc_ce_b  = (const float*)d_in[8];
    const float* fc2_w    = (const float*)d_in[9];
    const float* fc2_b    = (const float*)d_in[10];
    const float* fc_lwh_w = (const float*)d_in[11];
    const float* fc_lwh_b = (const float*)d_in[12];
    const float* fc3_w    = (const float*)d_in[13];
    const float* fc3_b    = (const float*)d_in[14];
    const float* fc_th_w  = (const float*)d_in[15];
    const float* fc_th_b  = (const float*)d_in[16];

    float* ws = (float*)d_ws;
    float* hx = ws + HX_OFF;
    float* hn = ws + HN_OFF;
    float* y  = ws + Y_OFF;
    float* st = ws + ST_OFF;
    int*  wcnt = (int*)(ws + WL_OFF);
    int*  wl   = wcnt + 1;
    int4* id4  = (int4*)(ws + ID4_OFF);
    float4* wp  = (float4*)(ws + WP_OFF);
    float4* pk4 = (float4*)(ws + PK_OFF);
    float* out = (float*)d_out;

    hipLaunchKernelGGL(k_prep,  dim3(144),  dim3(256), 0, stream,
                       x, fc1_w, fc2_w, fc3_w, st, wcnt, wp, pk4);
    hipLaunchKernelGGL(k_ball1, dim3(512),  dim3(256), 0, stream,
                       x, conv1_w, conv1_b, pk4, hx, hn, st, wcnt, wl, id4);
    hipLaunchKernelGGL(k_ball2, dim3(1024), dim3(256), 0, stream,
                       x, conv1_w, conv1_b, pk4, hx, hn, st, wcnt, wl, id4);
    hipLaunchKernelGGL(k_fc,    dim3(512),  dim3(256), 0, stream, hx, hn, st, wp,
                       fc1_b, fc2_b, fc3_b, bn_g, bn_b, y, out);
    hipLaunchKernelGGL(k_heads, dim3(512),  dim3(256), 0, stream, y, st,
                       fc_ce_w, fc_ce_b, fc_lwh_w, fc_lwh_b, fc_th_w, fc_th_b, bn_g, bn_b, out);
}